// Round 4
// baseline (146.704 us; speedup 1.0000x reference)
//
#include <hip/hip_runtime.h>
#include <hip/hip_bf16.h>

// GCNConv: out = A @ (X @ W)
// Stage 0: W_T[n][k] = bf16(W[k][n])                       (prep kernel, d_ws)
// Stage 1: Xp_bf16 = bf16(X @ W)   bf16 MFMA 16x16x32
//          A fragments direct global->reg (no cross-wave A reuse -> no A LDS)
// Stage 2: out[i,:] = sum_{e} Xp[colx[e],:]   2 nodes/wave, 8B gathers, fp32 acc

constexpr int D_IN  = 256;
constexpr int D_OUT = 128;
constexpr int BM = 128;
constexpr int BK = 32;
constexpr int LDA = BK + 8;   // padded LDS stride in shorts (40)

using short8  = __attribute__((ext_vector_type(8))) short;
using float4v = __attribute__((ext_vector_type(4))) float;

__device__ inline ushort f2bf(float f) {
    unsigned u = __float_as_uint(f);
    u = (u + 0x7FFFu + ((u >> 16) & 1u)) >> 16;   // RNE
    return (ushort)u;
}

__device__ inline uint pk2bf(float lo, float hi) {
    float2 t; t.x = lo; t.y = hi;
    __hip_bfloat162 b = __float22bfloat162_rn(t);   // v_cvt_pk_bf16_f32
    return *(uint*)&b;
}

// W[k][n] fp32 -> W_T[n][k] bf16  (128 rows x 256 cols)
__global__ __launch_bounds__(256) void prep_wt(const float* __restrict__ W,
                                               ushort* __restrict__ WT) {
    int id = blockIdx.x * 256 + threadIdx.x;   // 32768 total
    int nn = id >> 8;        // 0..127
    int k  = id & 255;       // 0..255
    WT[nn * 256 + k] = f2bf(W[k * D_OUT + nn]);
}

__global__ __launch_bounds__(256) void gemm_xw(const float* __restrict__ X,
                                               const ushort* __restrict__ WT,
                                               ushort* __restrict__ Xp, int n) {
    __shared__ ushort Bsl[D_OUT * LDA];  // 10 KB (B tile only)
    const int tid  = threadIdx.x;
    const int wave = tid >> 6;
    const int lane = tid & 63;
    const int quad = lane >> 4;
    const int l16  = lane & 15;
    const int row0 = blockIdx.x * BM;

    // A fragment source rows for this lane (clamped; stores are guarded)
    int rA = row0 + wave * 32 + l16;      if (rA > n - 1) rA = n - 1;
    int rB = row0 + wave * 32 + 16 + l16; if (rB > n - 1) rB = n - 1;
    const float* pA = X + (size_t)rA * D_IN + quad * 8;
    const float* pB = X + (size_t)rB * D_IN + quad * 8;

    float4v acc[2][8];
#pragma unroll
    for (int i = 0; i < 2; ++i)
#pragma unroll
        for (int t = 0; t < 8; ++t) acc[i][t] = (float4v){0.f, 0.f, 0.f, 0.f};

    for (int k0 = 0; k0 < D_IN; k0 += BK) {
        // A fragments: direct global -> reg, convert in-reg.
        // lane (quad,l16): A[m=l16][k=quad*8+j], 8 fp32 = 2 dwordx4 per row-tile.
        float4 x0 = *(const float4*)(pA + k0);
        float4 x1 = *(const float4*)(pA + k0 + 4);
        float4 y0 = *(const float4*)(pB + k0);
        float4 y1 = *(const float4*)(pB + k0 + 4);
        uint a0p[4] = { pk2bf(x0.x, x0.y), pk2bf(x0.z, x0.w),
                        pk2bf(x1.x, x1.y), pk2bf(x1.z, x1.w) };
        uint a1p[4] = { pk2bf(y0.x, y0.y), pk2bf(y0.z, y0.w),
                        pk2bf(y1.x, y1.y), pk2bf(y1.z, y1.w) };
        short8 a0 = *(short8*)a0p;
        short8 a1 = *(short8*)a1p;

        // Stage B tile: W_T rows 0..127, cols k0..k0+31. 512 short8, 2/thread.
#pragma unroll
        for (int i = 0; i < 2; ++i) {
            int idx = i * 256 + tid;
            int r  = idx >> 2;       // 4 chunks of 8 shorts per 32-short row
            int ch = idx & 3;
            short8 v = *(const short8*)(WT + r * 256 + k0 + ch * 8);
            *(short8*)(&Bsl[r * LDA + ch * 8]) = v;  // 16B aligned
        }
        __syncthreads();

#pragma unroll
        for (int t = 0; t < 8; ++t) {
            // B fragment: lane holds B[k=quad*8+j][nn = t*16 + l16]
            short8 b = *(const short8*)(&Bsl[(t * 16 + l16) * LDA + quad * 8]);
            acc[0][t] = __builtin_amdgcn_mfma_f32_16x16x32_bf16(a0, b, acc[0][t], 0, 0, 0);
            acc[1][t] = __builtin_amdgcn_mfma_f32_16x16x32_bf16(a1, b, acc[1][t], 0, 0, 0);
        }
        __syncthreads();
    }

    // Epilogue: C/D layout col = l16, row = quad*4 + reg
#pragma unroll
    for (int rt = 0; rt < 2; ++rt) {
#pragma unroll
        for (int t = 0; t < 8; ++t) {
#pragma unroll
            for (int r = 0; r < 4; ++r) {
                int row = row0 + wave * 32 + rt * 16 + quad * 4 + r;
                if (row < n)
                    Xp[(size_t)row * D_OUT + t * 16 + l16] = f2bf(acc[rt][t][r]);
            }
        }
    }
}

// 2 nodes per wave: 32 lanes per node, lane covers 4 of 128 cols (8B per edge).
// Degree-16 fast path: 16 gathers per node all in flight (32 per wave).
__global__ __launch_bounds__(256) void spmm_agg(const ushort* __restrict__ Xp,
                                                const int* __restrict__ rowp,
                                                const int* __restrict__ colx,
                                                float* __restrict__ out, int n) {
    const int lane   = threadIdx.x & 63;
    const int half   = lane >> 5;          // 0 or 1
    const int lane32 = lane & 31;
    const int node   = blockIdx.x * 8 + (threadIdx.x >> 6) * 2 + half;
    if (node >= n) return;
    const int e0 = rowp[node];
    const int e1 = rowp[node + 1];
    const ushort* src = Xp + lane32 * 4;   // 8B slice of the 256B row
    float4 acc = make_float4(0.f, 0.f, 0.f, 0.f);
    if (e1 - e0 == 16) {
        int c[16];
#pragma unroll
        for (int i = 0; i < 16; ++i) c[i] = colx[e0 + i];   // half-wave uniform
        uint2 v[16];
#pragma unroll
        for (int i = 0; i < 16; ++i)
            v[i] = *(const uint2*)(src + (size_t)c[i] * D_OUT);  // 16 in flight
#pragma unroll
        for (int i = 0; i < 16; ++i) {
            acc.x += __uint_as_float(v[i].x << 16);
            acc.y += __uint_as_float(v[i].x & 0xFFFF0000u);
            acc.z += __uint_as_float(v[i].y << 16);
            acc.w += __uint_as_float(v[i].y & 0xFFFF0000u);
        }
    } else {
        for (int e = e0; e < e1; ++e) {
            uint2 v = *(const uint2*)(src + (size_t)colx[e] * D_OUT);
            acc.x += __uint_as_float(v.x << 16);
            acc.y += __uint_as_float(v.x & 0xFFFF0000u);
            acc.z += __uint_as_float(v.y << 16);
            acc.w += __uint_as_float(v.y & 0xFFFF0000u);
        }
    }
    *(float4*)(out + (size_t)node * D_OUT + lane32 * 4) = acc;
}

extern "C" void kernel_launch(void* const* d_in, const int* in_sizes, int n_in,
                              void* d_out, int out_size, void* d_ws, size_t ws_size,
                              hipStream_t stream) {
    const float* X    = (const float*)d_in[0];
    const float* W    = (const float*)d_in[1];
    const int*   rowp = (const int*)d_in[2];
    const int*   colx = (const int*)d_in[3];
    float*       out  = (float*)d_out;

    ushort* WT = (ushort*)d_ws;                       // 128*256*2 = 64 KB
    ushort* Xp = (ushort*)((char*)d_ws + 65536);      // n*128*2 = 12.8 MB

    const int n = in_sizes[0] / D_IN;                 // 50000

    prep_wt<<<dim3(128), dim3(256), 0, stream>>>(W, WT);
    gemm_xw<<<dim3((n + BM - 1) / BM), dim3(256), 0, stream>>>(X, WT, Xp, n);
    spmm_agg<<<dim3((n + 7) / 8), dim3(256), 0, stream>>>(Xp, rowp, colx, out, n);
}